// Round 8
// baseline (412.512 us; speedup 1.0000x reference)
//
#include <hip/hip_runtime.h>
#include <hip/hip_cooperative_groups.h>

namespace cg = cooperative_groups;

#define A_N 8400
#define B_N 32
#define NGT 64
#define NC  80
#define BA  (B_N * A_N)
#define NCOL (B_N * NGT)
#define NBLK 512                 // cooperative grid: 2 blocks/CU, safely co-resident
#define ZB   192                 // zero-role blocks (phase A)
#define PB   (NBLK - ZB)         // pairs-role blocks (phase A)
#define NTILE (33 * B_N)         // 1056 anchor-tiles (256 anchors each)
#define ZVEC ((size_t)85 * BA / 4)  // float4s to zero = 5,712,000 (91.4 MB)

typedef float f4 __attribute__((ext_vector_type(4)));

// Single fused cooperative kernel.
// Phase A: blocks [0,ZB) stream-zero out[BA..86*BA) (write-BW-bound) WHILE
//          blocks [ZB,NBLK) run the pairs worklist (VALU/LDS-bound) -- the
//          overlap multi-stream capture can't express. Pairs logic identical
//          to r7 k_pairs (amf bit-identical to rounds 1-7, absmax 0.0).
// Phase B: 2048 waves == one per (b,gt) column, r7 k_topk logic lane-indexed.
// Phase C: r7 k_fin (dense labels + sparse fg writes into pre-zeroed region).
// NOTE: no early returns -- every thread reaches both grid syncs.
__global__ __launch_bounds__(256) void k_fused(
    const float* __restrict__ pd_s, const float* __restrict__ pd_b,
    const float* __restrict__ anc, const int* __restrict__ gt_l,
    const float* __restrict__ gt_b, const int* __restrict__ mgt,
    unsigned long long* __restrict__ lists, int* __restrict__ cnts, int cap,
    unsigned long long* __restrict__ recs, unsigned* __restrict__ mn_g,
    unsigned* __restrict__ mx_g, float* __restrict__ out) {
#pragma clang fp contract(off)
  cg::grid_group grid = cg::this_grid();
  int tid = threadIdx.x;
  int bk = blockIdx.x;

  __shared__ float4 gb_s[NGT];
  __shared__ int lab_s[NGT];
  __shared__ float4 pb_s[256];
  __shared__ unsigned long long key_s[256];
  __shared__ unsigned short wl[256 * 64];  // 32 KB worst-case worklist
  __shared__ int wl_cnt;
  __shared__ int cnt_sh;

  // ------------------------------ PHASE A --------------------------------
  if (bk < ZB) {
    // zero role: 91.4 MB of bbox/scores/fg region, coalesced grid-stride
    f4 z = {0.f, 0.f, 0.f, 0.f};
    f4* dst = (f4*)(out + BA);
    for (size_t v = (size_t)bk * 256 + tid; v < ZVEC; v += (size_t)ZB * 256)
      __builtin_nontemporal_store(z, &dst[v]);
  } else {
    // pairs role: tiles strided over PB blocks
    int pr = bk - ZB;
    for (int t = pr; t < NTILE; t += PB) {
      int b = t / 33, bx = t - b * 33;
      int a0 = bx * 256, a = a0 + tid;
      bool av = a < A_N;

      if (tid < NGT) {
        gb_s[tid] = ((const float4*)gt_b)[b * NGT + tid];
        lab_s[tid] = gt_l[b * NGT + tid];
        unsigned long long mm = __ballot(mgt[b * NGT + tid] != 0);  // prefix
        if (tid == 0) cnt_sh = __popcll(mm);
      }
      float4 pb = av ? ((const float4*)pd_b)[(size_t)b * A_N + a]
                     : make_float4(0.f, 0.f, 0.f, 0.f);
      float2 ap = av ? ((const float2*)anc)[a] : make_float2(-1e30f, -1e30f);
      pb_s[tid] = pb;
      key_s[tid] = (unsigned long long)(63 << 1);  // (v=0,n=0,fg=0) default
      if (tid == 0) wl_cnt = 0;
      __syncthreads();
      int cnt = cnt_sh;

      // in-box AND pred-overlap test; failures have v == +0.0 exactly
      if (av) {
        for (int n = 0; n < cnt; n++) {
          float4 gb = gb_s[n];
          float mn = fminf(fminf(ap.x - gb.x, ap.y - gb.y),
                           fminf(gb.z - ap.x, gb.w - ap.y));
          float iwr = fminf(gb.z, pb.z) - fmaxf(gb.x, pb.x);
          float ihr = fminf(gb.w, pb.w) - fmaxf(gb.y, pb.y);
          if (mn > 0.0f && iwr > 0.0f && ihr > 0.0f) {
            int p = atomicAdd(&wl_cnt, 1);
            wl[p] = (unsigned short)((tid << 6) | n);
          }
        }
      }
      __syncthreads();
      int m = wl_cnt;

      // cooperative drain: scattered pd_s gathers with full MLP
      for (int i = tid; i < m; i += 256) {
        int e = wl[i];
        int al = e >> 6, n = e & 63;
        int ag = a0 + al;
        float4 gb = gb_s[n];
        float4 pbl = pb_s[al];
        float iw = fmaxf(fminf(gb.z, pbl.z) - fmaxf(gb.x, pbl.x), 0.0f);
        float ih = fmaxf(fminf(gb.w, pbl.w) - fmaxf(gb.y, pbl.y), 0.0f);
        float inter = iw * ih;
        float w1 = gb.z - gb.x, h1 = (gb.w - gb.y) + 1e-16f;
        float w2 = pbl.z - pbl.x, h2 = (pbl.w - pbl.y) + 1e-16f;
        float uni = ((w1 * h1 + w2 * h2) - inter) + 1e-16f;
        float iou = inter / uni;
        float sc = pd_s[((size_t)b * A_N + ag) * NC + (size_t)lab_s[n]];
        float v = sqrtf(sc) * powf(iou, 6.0f);
        if (v > 0.0f) {
          unsigned vb = __float_as_uint(v);
          int col = b * NGT + n;
          int pos = atomicAdd(&cnts[col], 1);
          if (pos < cap) {
            lists[(size_t)col * cap + pos] =
                ((unsigned long long)vb << 32) |
                (unsigned long long)(0xFFFFFFFFu - (unsigned)ag);
          }
          atomicMax(&key_s[al], ((unsigned long long)vb << 32) |
                                    (unsigned long long)((63 - n) << 1));
        }
      }
      __syncthreads();
      if (av) recs[(size_t)b * A_N + a] = key_s[tid];
      // next tile's init only touches per-thread-owned slots before its
      // barrier -> no extra barrier needed here
    }
  }

  __threadfence();
  grid.sync();

  // ------------------------------ PHASE B --------------------------------
  // exactly NBLK*4 == 2048 waves; wave w handles column w (b = w>>6, n = w&63)
  {
    int lane = tid & 63;
    int col = bk * 4 + (tid >> 6);
    unsigned* recw = (unsigned*)recs;  // [2i]=fg|gt bits, [2i+1]=am_max bits
    unsigned loc_mn = 0xFFFFFFFFu, loc_mx = 0u;  // uint-order identities
    if (mgt[col] != 0) {  // wave-uniform branch
      int b = col >> 6;
      int P = cnts[col];
      if (P > cap) P = cap;
      const unsigned long long* list = lists + (size_t)col * cap;

      if (P >= 10) {
        unsigned long long top[10];
#pragma unroll
        for (int j = 0; j < 10; j++) top[j] = 0ull;
        for (int i = lane; i < P; i += 64) {
          unsigned long long key = list[i];
#pragma unroll
          for (int j = 0; j < 10; j++) {
            if (key > top[j]) { unsigned long long tt = top[j]; top[j] = key; key = tt; }
          }
        }
        for (int r = 0; r < 10; r++) {
          unsigned long long g = top[0];
#pragma unroll
          for (int off = 32; off >= 1; off >>= 1) {
            unsigned long long o = __shfl_xor(g, off, 64);
            g = (o > g) ? o : g;
          }
          if (top[0] == g) {  // unique keys -> exactly one lane pops
#pragma unroll
            for (int j = 0; j < 9; j++) top[j] = top[j + 1];
            top[9] = 0ull;
          }
          if (lane == r) {
            size_t idx = (size_t)b * A_N +
                         (size_t)(0xFFFFFFFFu - (unsigned)(g & 0xFFFFFFFFull));
            atomicOr(&recw[2 * idx], 1u);
            unsigned u = recw[2 * idx + 1];
            loc_mn = (u < loc_mn) ? u : loc_mn;
            loc_mx = (u > loc_mx) ? u : loc_mx;
          }
        }
      } else {
        // positives all win (lanes 0..P-1)
        int my_a = -1;
        if (lane < P)
          my_a = (int)(0xFFFFFFFFu - (unsigned)(list[lane] & 0xFFFFFFFFull));
        if (lane < P) {
          size_t idx = (size_t)b * A_N + my_a;
          atomicOr(&recw[2 * idx], 1u);
          unsigned u = recw[2 * idx + 1];
          loc_mn = (u < loc_mn) ? u : loc_mn;
          loc_mx = (u > loc_mx) ? u : loc_mx;
        }
        // zero-tie winners: first (10-P) anchor indices not in the positive
        // set (all within [0,19) since P <= 9); slot consumed regardless,
        // fg only if in-box (jax.lax.top_k stable tie-break)
        bool is_pos = false;
        for (int i = 0; i < P; i++) {
          int ai = __shfl(my_a, i, 64);
          is_pos |= (ai == lane);
        }
        bool cand = (lane < 19) && !is_pos;
        unsigned long long fm = __ballot(cand);
        int rank = __popcll(fm & ((1ull << lane) - 1ull));
        if (cand && rank < 10 - P) {
          int n = col & 63;
          float4 gb = ((const float4*)gt_b)[b * NGT + n];
          float2 ap = ((const float2*)anc)[lane];
          float mn = fminf(fminf(ap.x - gb.x, ap.y - gb.y),
                           fminf(gb.z - ap.x, gb.w - ap.y));
          if (mn > 0.0f) {
            size_t idx = (size_t)b * A_N + lane;
            atomicOr(&recw[2 * idx], 1u);
            unsigned u = recw[2 * idx + 1];
            loc_mn = (u < loc_mn) ? u : loc_mn;
            loc_mx = (u > loc_mx) ? u : loc_mx;
          }
        }
      }
      // wave-local fold -> at most one atomicMin+atomicMax per wave
#pragma unroll
      for (int off = 32; off >= 1; off >>= 1) {
        unsigned o1 = __shfl_xor(loc_mn, off, 64);
        loc_mn = (o1 < loc_mn) ? o1 : loc_mn;
        unsigned o2 = __shfl_xor(loc_mx, off, 64);
        loc_mx = (o2 > loc_mx) ? o2 : loc_mx;
      }
      if (lane == 0 && loc_mn != 0xFFFFFFFFu) {
        atomicMin(&mn_g[b], loc_mn);
        atomicMax(&mx_g[b], loc_mx);
      }
    }
  }

  __threadfence();
  grid.sync();

  // ------------------------------ PHASE C --------------------------------
  for (int t = bk; t < NTILE; t += NBLK) {
    int b = t / 33, bx = t - b * 33;
    int a = bx * 256 + tid;
    if (a < A_N) {
      size_t i = (size_t)b * A_N + a;
      unsigned long long rec = recs[i];
      bool fg = (rec & 1ull) != 0;
      int bi = 63 - (int)((rec >> 1) & 63ull);
      int lab = gt_l[b * NGT + bi];
      out[i] = fg ? (float)lab : (float)NC;  // t_labels (dense)
      if (fg) {
        float amx = __uint_as_float((unsigned)(rec >> 32));
        float mn = __uint_as_float(mn_g[b]);
        float mx = __uint_as_float(mx_g[b]);
        float norm = (amx - mn) / ((mx - mn) + 1e-9f);
        float4 tt = ((const float4*)gt_b)[b * NGT + bi];
        f4 bb = {tt.x, tt.y, tt.z, tt.w};
        ((f4*)(out + BA))[i] = bb;                          // t_bboxes
        out[(size_t)85 * BA + i] = 1.0f;                    // fg
        out[(size_t)5 * BA + i * NC + (size_t)lab] = norm;  // one-hot score
      }
    }
  }
}

extern "C" void kernel_launch(void* const* d_in, const int* in_sizes, int n_in,
                              void* d_out, int out_size, void* d_ws,
                              size_t ws_size, hipStream_t stream) {
  const float* pd_s = (const float*)d_in[0];   // (B, A, 80)
  const float* pd_b = (const float*)d_in[1];   // (B, A, 4)
  const float* anc  = (const float*)d_in[2];   // (A, 2)
  const int*   gt_l = (const int*)d_in[3];     // (B, 64, 1)
  const float* gt_b = (const float*)d_in[4];   // (B, 64, 4)
  const int*   mgt  = (const int*)d_in[5];     // (B, 64, 1)

  float* out = (float*)d_out;
  char* ws = (char*)d_ws;

  // layout: lists | recs | cnts | mx_g | mn_g
  const size_t REC_BYTES = (size_t)BA * 8;
  size_t small_bytes = REC_BYTES + (size_t)NCOL * 4 + 256;
  size_t avail = (ws_size > small_bytes) ? (ws_size - small_bytes) : 0;
  int cap = (int)(avail / ((size_t)NCOL * 8));
  if (cap > 4096) cap = 4096;
  if (cap < 1) cap = 1;

  unsigned long long* lists = (unsigned long long*)ws;
  char* sb = ws + (size_t)NCOL * 8 * cap;
  unsigned long long* recs = (unsigned long long*)sb;
  int*      cnts = (int*)(sb + REC_BYTES);
  unsigned* mx_g = (unsigned*)(sb + REC_BYTES + (size_t)NCOL * 4);
  unsigned* mn_g = mx_g + B_N;

  // cnts + mx_g zero in one fill; mn_g = 0xFFFFFFFF (uint-min identity; never
  // a valid am_max bit pattern -- that would be NaN)
  hipMemsetAsync(cnts, 0, (size_t)NCOL * 4 + (size_t)B_N * 4, stream);
  hipMemsetAsync(mn_g, 0xFF, (size_t)B_N * 4, stream);

  void* kargs[] = {(void*)&pd_s, (void*)&pd_b, (void*)&anc,  (void*)&gt_l,
                   (void*)&gt_b, (void*)&mgt,  (void*)&lists, (void*)&cnts,
                   (void*)&cap,  (void*)&recs, (void*)&mn_g, (void*)&mx_g,
                   (void*)&out};
  hipLaunchCooperativeKernel((const void*)k_fused, dim3(NBLK), dim3(256),
                             kargs, 0, stream);
}

// Round 9
// 182.633 us; speedup vs baseline: 2.2587x; 2.2587x over previous
//
#include <hip/hip_runtime.h>

#define A_N 8400
#define B_N 32
#define NGT 64
#define NC  80
#define BA  (B_N * A_N)
#define NCOL (B_N * NGT)

typedef float f4 __attribute__((ext_vector_type(4)));

// ---------------------------------------------------------------------------
// Pass 1: block = 256 anchors of one batch, single-pass worklist (r7).
// Phase 1: register-only in-box AND pred-overlap test (failures have
// v == +0.0 exactly -> no effect on any decision), push to LDS worklist.
// Phase 2: cooperative drain -- scattered pd_s gathers with full MLP + amf
// (bit-identical expression to rounds 1-7, contract off, verified absmax 0.0).
// Results: per-column candidate lists + per-anchor argmax via LDS atomicMax
// on key = (vbits<<32)|((63-n)<<1) (max v, tie -> min n; bit 0 = fg).
// NOTE (r8 post-mortem): do NOT fuse these passes with grid.sync --
// cooperative-grid barriers cost ~100us+ on gfx950 at 512 blocks.
// ---------------------------------------------------------------------------
__global__ __launch_bounds__(256) void k_pairs(
    const float* __restrict__ pd_s, const float* __restrict__ pd_b,
    const float* __restrict__ anc, const int* __restrict__ gt_l,
    const float* __restrict__ gt_b, const int* __restrict__ mgt,
    unsigned long long* __restrict__ lists, int* __restrict__ cnts, int cap,
    unsigned long long* __restrict__ recs) {
#pragma clang fp contract(off)
  int b = blockIdx.y, tid = threadIdx.x;
  int a0 = blockIdx.x * 256, a = a0 + tid;
  bool av = a < A_N;

  __shared__ float4 gb_s[NGT];
  __shared__ int lab_s[NGT];
  __shared__ float4 pb_s[256];
  __shared__ unsigned long long key_s[256];
  __shared__ unsigned short wl[256 * 64];  // 32 KB: exact worst case
  __shared__ int wl_cnt;
  __shared__ int cnt_sh;

  if (tid < NGT) {
    gb_s[tid] = ((const float4*)gt_b)[b * NGT + tid];
    lab_s[tid] = gt_l[b * NGT + tid];
    unsigned long long m = __ballot(mgt[b * NGT + tid] != 0);  // prefix mask
    if (tid == 0) cnt_sh = __popcll(m);
  }
  float4 pb = av ? ((const float4*)pd_b)[(size_t)b * A_N + a]
                 : make_float4(0.f, 0.f, 0.f, 0.f);
  float2 ap = av ? ((const float2*)anc)[a] : make_float2(-1e30f, -1e30f);
  pb_s[tid] = pb;
  key_s[tid] = (unsigned long long)(63 << 1);  // (v=0, n=0, fg=0) default
  if (tid == 0) wl_cnt = 0;
  __syncthreads();
  int cnt = cnt_sh;

  // phase 1: one sweep over all valid gts (~0.04% of pairs pass both tests)
  if (av) {
    for (int n = 0; n < cnt; n++) {
      float4 gb = gb_s[n];
      float mn = fminf(fminf(ap.x - gb.x, ap.y - gb.y),
                       fminf(gb.z - ap.x, gb.w - ap.y));
      float iwr = fminf(gb.z, pb.z) - fmaxf(gb.x, pb.x);
      float ihr = fminf(gb.w, pb.w) - fmaxf(gb.y, pb.y);
      if (mn > 0.0f && iwr > 0.0f && ihr > 0.0f) {
        int p = atomicAdd(&wl_cnt, 1);
        wl[p] = (unsigned short)((tid << 6) | n);
      }
    }
  }
  __syncthreads();
  int m = wl_cnt;

  // phase 2: cooperative drain (~14 items/block typical), full-MLP gathers
  for (int i = tid; i < m; i += 256) {
    int e = wl[i];
    int al = e >> 6, n = e & 63;
    int ag = a0 + al;
    float4 gb = gb_s[n];
    float4 pbl = pb_s[al];
    float iw = fmaxf(fminf(gb.z, pbl.z) - fmaxf(gb.x, pbl.x), 0.0f);
    float ih = fmaxf(fminf(gb.w, pbl.w) - fmaxf(gb.y, pbl.y), 0.0f);
    float inter = iw * ih;
    float w1 = gb.z - gb.x, h1 = (gb.w - gb.y) + 1e-16f;
    float w2 = pbl.z - pbl.x, h2 = (pbl.w - pbl.y) + 1e-16f;
    float uni = ((w1 * h1 + w2 * h2) - inter) + 1e-16f;
    float iou = inter / uni;
    float sc = pd_s[((size_t)b * A_N + ag) * NC + (size_t)lab_s[n]];
    float v = sqrtf(sc) * powf(iou, 6.0f);
    if (v > 0.0f) {
      unsigned vb = __float_as_uint(v);
      int col = b * NGT + n;
      int pos = atomicAdd(&cnts[col], 1);
      if (pos < cap) {
        lists[(size_t)col * cap + pos] =
            ((unsigned long long)vb << 32) |
            (unsigned long long)(0xFFFFFFFFu - (unsigned)ag);
      }
      atomicMax(&key_s[al], ((unsigned long long)vb << 32) |
                                (unsigned long long)((63 - n) << 1));
    }
  }
  __syncthreads();

  if (av) recs[(size_t)b * A_N + a] = key_s[tid];
}

// ---------------------------------------------------------------------------
// Pass 2: per (b, gt) column, one wave. Winners = top-10 by (v desc, a asc)
// over the full 8400 column (jax.lax.top_k stable semantics). Positives from
// the list; if P < 10 the remaining winners are the smallest-index
// zero-valued anchors (all within [0,19) since P <= 9), wave-parallel via
// ballot rank; only in-box ones become fg (atomicOr bit 0 of the record).
// Per-batch min/max folded wave-locally -> one atomic pair per block (r5).
// ROUND 9: min tracked as COMPLEMENT (negmn = max ~u, identity 0) so all
// small state (cnts, mx_g, negmn_g) is zero-init -> k_init kernel removed.
// ---------------------------------------------------------------------------
__global__ __launch_bounds__(64) void k_topk(
    const unsigned long long* __restrict__ lists, const int* __restrict__ cnts,
    int cap, const int* __restrict__ mgt, const float* __restrict__ anc,
    const float* __restrict__ gt_b, unsigned long long* __restrict__ recs,
    unsigned* __restrict__ negmn_g, unsigned* __restrict__ mx_g) {
  int b = blockIdx.x, n = blockIdx.y, tid = threadIdx.x;
  if (mgt[b * NGT + n] == 0) return;
  int col = b * NGT + n;
  int P = cnts[col];
  if (P > cap) P = cap;
  const unsigned long long* list = lists + (size_t)col * cap;
  unsigned* recw = (unsigned*)recs;  // [2i]=fg|gt bits, [2i+1]=am_max bits

  unsigned loc_negmn = 0u, loc_mx = 0u;  // zero identities (am_max >= 0)
  bool any = false;

  if (P >= 10) {
    // All 10 winners positive => in_gts guaranteed.
    unsigned long long top[10];
#pragma unroll
    for (int j = 0; j < 10; j++) top[j] = 0ull;
    for (int i = tid; i < P; i += 64) {
      unsigned long long key = list[i];
#pragma unroll
      for (int j = 0; j < 10; j++) {
        if (key > top[j]) { unsigned long long t = top[j]; top[j] = key; key = t; }
      }
    }
    for (int r = 0; r < 10; r++) {
      unsigned long long g = top[0];
#pragma unroll
      for (int off = 32; off >= 1; off >>= 1) {
        unsigned long long o = __shfl_xor(g, off, 64);
        g = (o > g) ? o : g;
      }
      if (top[0] == g) {  // unique keys -> exactly one lane pops
#pragma unroll
        for (int j = 0; j < 9; j++) top[j] = top[j + 1];
        top[9] = 0ull;
      }
      if (tid == r) {
        size_t idx = (size_t)b * A_N +
                     (size_t)(0xFFFFFFFFu - (unsigned)(g & 0xFFFFFFFFull));
        atomicOr(&recw[2 * idx], 1u);
        unsigned u = recw[2 * idx + 1];
        unsigned nu = ~u;
        loc_negmn = (nu > loc_negmn) ? nu : loc_negmn;
        loc_mx = (u > loc_mx) ? u : loc_mx;
        any = true;
      }
    }
  } else {
    // Positives all win (lanes 0..P-1).
    int my_a = -1;
    if (tid < P)
      my_a = (int)(0xFFFFFFFFu - (unsigned)(list[tid] & 0xFFFFFFFFull));
    if (tid < P) {
      size_t idx = (size_t)b * A_N + my_a;
      atomicOr(&recw[2 * idx], 1u);
      unsigned u = recw[2 * idx + 1];
      unsigned nu = ~u;
      loc_negmn = (nu > loc_negmn) ? nu : loc_negmn;
      loc_mx = (u > loc_mx) ? u : loc_mx;
      any = true;
    }
    // Zero-tie winners: first (10-P) anchor indices not in the positive set
    // (slot consumed regardless; fg only if in-box).
    bool is_pos = false;
    for (int i = 0; i < P; i++) {
      int ai = __shfl(my_a, i, 64);
      is_pos |= (ai == tid);
    }
    bool cand = (tid < 19) && !is_pos;
    unsigned long long fm = __ballot(cand);
    int rank = __popcll(fm & ((1ull << tid) - 1ull));
    if (cand && rank < 10 - P) {
      float4 gb = ((const float4*)gt_b)[b * NGT + n];
      float2 ap = ((const float2*)anc)[tid];
      float mn = fminf(fminf(ap.x - gb.x, ap.y - gb.y),
                       fminf(gb.z - ap.x, gb.w - ap.y));
      if (mn > 0.0f) {
        size_t idx = (size_t)b * A_N + tid;
        atomicOr(&recw[2 * idx], 1u);
        unsigned u = recw[2 * idx + 1];
        unsigned nu = ~u;
        loc_negmn = (nu > loc_negmn) ? nu : loc_negmn;
        loc_mx = (u > loc_mx) ? u : loc_mx;
        any = true;
      }
    }
  }

  // wave-local fold -> one atomic pair per block
  unsigned long long am = __ballot(any);
#pragma unroll
  for (int off = 32; off >= 1; off >>= 1) {
    unsigned o1 = __shfl_xor(loc_negmn, off, 64);
    loc_negmn = (o1 > loc_negmn) ? o1 : loc_negmn;
    unsigned o2 = __shfl_xor(loc_mx, off, 64);
    loc_mx = (o2 > loc_mx) ? o2 : loc_mx;
  }
  if (tid == 0 && am != 0ull) {
    atomicMax(&negmn_g[b], loc_negmn);
    atomicMax(&mx_g[b], loc_mx);
  }
}

// ---------------------------------------------------------------------------
// Finalize: bboxes/scores/fg pre-zeroed by hipMemsetAsync (91.4 MB at fill
// BW). Writes the dense label plane + sparse per-fg data (bbox, fg flag,
// ONE one-hot score scalar).
// ---------------------------------------------------------------------------
__global__ __launch_bounds__(256) void k_fin(
    const int* __restrict__ gt_l, const float* __restrict__ gt_b,
    const unsigned long long* __restrict__ recs,
    const unsigned* __restrict__ negmn_g, const unsigned* __restrict__ mx_g,
    float* __restrict__ out) {
  int b = blockIdx.y;
  int a = blockIdx.x * 256 + threadIdx.x;
  if (a >= A_N) return;
  size_t i = (size_t)b * A_N + a;
  unsigned long long rec = recs[i];
  bool fg = (rec & 1ull) != 0;
  int bi = 63 - (int)((rec >> 1) & 63ull);
  int lab = gt_l[b * NGT + bi];

  out[i] = fg ? (float)lab : (float)NC;  // t_labels (dense)
  if (fg) {
    float amx = __uint_as_float((unsigned)(rec >> 32));
    float mn = __uint_as_float(~negmn_g[b]);
    float mx = __uint_as_float(mx_g[b]);
    float norm = (amx - mn) / ((mx - mn) + 1e-9f);
    float4 t = ((const float4*)gt_b)[b * NGT + bi];
    f4 bb = {t.x, t.y, t.z, t.w};
    ((f4*)(out + BA))[i] = bb;                          // t_bboxes
    out[(size_t)85 * BA + i] = 1.0f;                    // fg
    out[(size_t)5 * BA + i * NC + (size_t)lab] = norm;  // one-hot score
  }
}

extern "C" void kernel_launch(void* const* d_in, const int* in_sizes, int n_in,
                              void* d_out, int out_size, void* d_ws,
                              size_t ws_size, hipStream_t stream) {
  const float* pd_s = (const float*)d_in[0];   // (B, A, 80)
  const float* pd_b = (const float*)d_in[1];   // (B, A, 4)
  const float* anc  = (const float*)d_in[2];   // (A, 2)
  const int*   gt_l = (const int*)d_in[3];     // (B, 64, 1)
  const float* gt_b = (const float*)d_in[4];   // (B, 64, 4)
  const int*   mgt  = (const int*)d_in[5];     // (B, 64, 1)

  float* out = (float*)d_out;
  char* ws = (char*)d_ws;

  // layout: lists | recs | cnts | negmn_g | mx_g   (cnts..mx_g all zero-init)
  const size_t REC_BYTES = (size_t)BA * 8;
  size_t small_bytes = REC_BYTES + (size_t)NCOL * 4 + (size_t)2 * B_N * 4 + 256;
  size_t avail = (ws_size > small_bytes) ? (ws_size - small_bytes) : 0;
  int cap = (int)(avail / ((size_t)NCOL * 8));
  if (cap > A_N) cap = A_N;  // cap=8400 == provably no list overflow
  if (cap < 1) cap = 1;

  unsigned long long* lists = (unsigned long long*)ws;
  char* sb = ws + (size_t)NCOL * 8 * cap;
  unsigned long long* recs = (unsigned long long*)sb;
  int*      cnts   = (int*)(sb + REC_BYTES);
  unsigned* negmn_g = (unsigned*)(sb + REC_BYTES + (size_t)NCOL * 4);
  unsigned* mx_g   = negmn_g + B_N;

  // Pre-zero bboxes+scores+fg regions [BA, 86*BA): 91.4 MB at fill-kernel BW.
  hipMemsetAsync(out + BA, 0, (size_t)85 * BA * 4, stream);
  // cnts + negmn + mx in one tiny fill (all zero identities -- r9 trick).
  hipMemsetAsync(cnts, 0, (size_t)NCOL * 4 + (size_t)2 * B_N * 4, stream);

  dim3 g2((A_N + 255) / 256, B_N);
  k_pairs<<<g2, 256, 0, stream>>>(pd_s, pd_b, anc, gt_l, gt_b, mgt, lists,
                                  cnts, cap, recs);
  k_topk<<<dim3(B_N, NGT), 64, 0, stream>>>(lists, cnts, cap, mgt, anc, gt_b,
                                            recs, negmn_g, mx_g);
  k_fin<<<g2, 256, 0, stream>>>(gt_l, gt_b, recs, negmn_g, mx_g, out);
}